// Round 4
// baseline (1026.762 us; speedup 1.0000x reference)
//
#include <hip/hip_runtime.h>
#include <math.h>

// Fused Conv3d(3->16, k=3, valid) + bias + min over D + softmax over C.
// N=16, CIN=3, COUT=16, K=3, D=H=W=64 -> out [16,16,62,62] fp32.
//
// R4: co is WAVE-uniform (block = 1024 = 16 waves = 16 output channels).
// The 81 conv weights per co are wave-uniform -> pinned to SGPRs via
// readfirstlane (v_fma takes 1 SGPR operand), freeing ~81 VGPRs vs R3
// (R3: VGPR=228 -> 2 waves/SIMD, 11% occupancy, VALUBusy 62%).
// Each lane: 1x4 pixel strip; tile 16x16/block; grid 4x4x16 = 256 blocks.
// Depth-streaming ring of 3 accumulators handles kd; min over d' online.
// Softmax over co needs a cross-wave LDS transpose at the epilogue.

#define CH 8  // d-slices per staged chunk

__global__ __launch_bounds__(1024) void conv3d_min_softmax(
    const float* __restrict__ x,     // [16,3,64,64,64]
    const float* __restrict__ wgt,   // [16,3,3,3,3]
    const float* __restrict__ bias,  // [16]
    float* __restrict__ out)         // [16,16,62,62]
{
    const int tid  = threadIdx.x;
    const int lane = tid & 63;
    const int wv   = __builtin_amdgcn_readfirstlane(tid >> 6); // co, uniform
    const int lh   = lane >> 2;         // 0..15: output row in tile
    const int lw   = (lane & 3) * 4;    // 0,4,8,12: strip col base
    const int n  = blockIdx.z;
    const int h0 = blockIdx.y * 16;     // 4 h-tiles cover rows 0..63
    const int w0 = blockIdx.x * 16;     // 4 w-tiles cover cols 0..63

    // staged x: 3 ci x CH d x 18 rows x 20 cols (18 valid; stride 20 keeps
    // float4 alignment). 34.5 KB.
    __shared__ __align__(16) float sx[3][CH][18][20];
    // epilogue transpose: [co][pixel] for the 16x16 tile. 16 KB.
    __shared__ __align__(16) float sm[16][256];

    // per-wave weights, forced uniform -> SGPR file.
    // idx = ci*27 + kd*9 + kh*3 + kw
    float wreg[81];
#pragma unroll
    for (int i = 0; i < 81; ++i)
        wreg[i] = __uint_as_float(__builtin_amdgcn_readfirstlane(
            __float_as_uint(wgt[wv * 81 + i])));

    // ring: A0 completes this step (kd=2), A1 next (kd=1), A2 after (kd=0)
    float A0[4], A1[4], A2[4], mv[4];
#pragma unroll
    for (int p = 0; p < 4; ++p) {
        A0[p] = A1[p] = A2[p] = 0.f;
        mv[p] = 1e30f;
    }

    const float* xn = x + (size_t)n * 3 * 64 * 64 * 64;

    for (int c = 0; c < 64 / CH; ++c) {
        const int d0 = c * CH;
        __syncthreads();
        // ---- stage 3 x CH x 18 x 18(->20) slice: 2160 float4 ----
        for (int F = tid; F < 3 * CH * 18 * 5; F += 1024) {
            int rowid = F / 5;               // ci*(CH*18) + dd*18 + r
            int g     = F - rowid * 5;       // col group (4 floats)
            int ci    = rowid / (CH * 18);
            int rem   = rowid - ci * (CH * 18);
            int dd    = rem / 18;
            int r     = rem - dd * 18;
            int gh    = min(h0 + r, 63);     // clamp: edge halo, unused
            int gw    = min(w0 + g * 4, 60); // clamp: cols >=62 unused
            *(float4*)&sx[ci][dd][r][g * 4] = *(const float4*)
                &xn[(((size_t)ci * 64 + d0 + dd) * 64 + gh) * 64 + gw];
        }
        __syncthreads();

        // ---- compute CH d-steps from LDS: 324 FMA per lane per d-step ----
#pragma unroll 2
        for (int dd = 0; dd < CH; ++dd) {
#pragma unroll
            for (int ci = 0; ci < 3; ++ci) {
#pragma unroll
                for (int r = 0; r < 3; ++r) {   // window row == kh
                    const float4 a = *(const float4*)&sx[ci][dd][lh + r][lw];
                    const float2 b = *(const float2*)&sx[ci][dd][lh + r][lw + 4];
                    const float row[6] = {a.x, a.y, a.z, a.w, b.x, b.y};
#pragma unroll
                    for (int kw = 0; kw < 3; ++kw) {
                        const float wk0 = wreg[ci * 27 + 0  + r * 3 + kw];
                        const float wk1 = wreg[ci * 27 + 9  + r * 3 + kw];
                        const float wk2 = wreg[ci * 27 + 18 + r * 3 + kw];
#pragma unroll
                        for (int p = 0; p < 4; ++p) {
                            const float xv = row[kw + p];
                            A2[p] = fmaf(xv, wk0, A2[p]); // d' = d
                            A1[p] = fmaf(xv, wk1, A1[p]); // d' = d-1
                            A0[p] = fmaf(xv, wk2, A0[p]); // d' = d-2
                        }
                    }
                }
            }
            if (d0 + dd >= 2) {                 // wave-uniform branch
#pragma unroll
                for (int p = 0; p < 4; ++p) mv[p] = fminf(mv[p], A0[p]);
            }
#pragma unroll
            for (int p = 0; p < 4; ++p) {
                A0[p] = A1[p]; A1[p] = A2[p]; A2[p] = 0.f;
            }
        }
    }

    // ---- epilogue: bias, cross-wave softmax over the 16 co, store ----
    const float bv = __uint_as_float(__builtin_amdgcn_readfirstlane(
        __float_as_uint(bias[wv])));
    const int pxb = lane * 4;   // == lh*16 + lw: pixel base in tile
    *(float4*)&sm[wv][pxb] =
        make_float4(mv[0] + bv, mv[1] + bv, mv[2] + bv, mv[3] + bv);
    __syncthreads();

    float mx[4] = {-1e30f, -1e30f, -1e30f, -1e30f};
#pragma unroll
    for (int c2 = 0; c2 < 16; ++c2) {
        const float4 v = *(const float4*)&sm[c2][pxb];
        mx[0] = fmaxf(mx[0], v.x); mx[1] = fmaxf(mx[1], v.y);
        mx[2] = fmaxf(mx[2], v.z); mx[3] = fmaxf(mx[3], v.w);
    }
    float sum[4] = {0.f, 0.f, 0.f, 0.f};
#pragma unroll
    for (int c2 = 0; c2 < 16; ++c2) {
        const float4 v = *(const float4*)&sm[c2][pxb];
        sum[0] += __expf(v.x - mx[0]); sum[1] += __expf(v.y - mx[1]);
        sum[2] += __expf(v.z - mx[2]); sum[3] += __expf(v.w - mx[3]);
    }
    const float4 own = *(const float4*)&sm[wv][pxb];
    const float e[4] = {__expf(own.x - mx[0]) / sum[0],
                        __expf(own.y - mx[1]) / sum[1],
                        __expf(own.z - mx[2]) / sum[2],
                        __expf(own.w - mx[3]) / sum[3]};
    const int hp = h0 + lh;
#pragma unroll
    for (int p = 0; p < 4; ++p) {
        const int wp = w0 + lw + p;
        if (hp < 62 && wp < 62)
            out[(((size_t)n * 16 + wv) * 62 + hp) * 62 + wp] = e[p];
    }
}

extern "C" void kernel_launch(void* const* d_in, const int* in_sizes, int n_in,
                              void* d_out, int out_size, void* d_ws, size_t ws_size,
                              hipStream_t stream) {
    const float* x    = (const float*)d_in[0];
    const float* wgt  = (const float*)d_in[1];
    const float* bias = (const float*)d_in[2];
    float* out        = (float*)d_out;
    dim3 grid(4, 4, 16);   // (w-tiles, h-tiles, n) = 256 blocks, 1/CU
    dim3 block(1024);      // 16 waves = 16 output channels
    hipLaunchKernelGGL(conv3d_min_softmax, grid, block, 0, stream,
                       x, wgt, bias, out);
}

// Round 5
// 309.121 us; speedup vs baseline: 3.3216x; 3.3216x over previous
//
#include <hip/hip_runtime.h>
#include <math.h>

// Fused Conv3d(3->16, k=3, valid) + bias + min over D + softmax over C.
// N=16, CIN=3, COUT=16, K=3, D=H=W=64 -> out [16,16,62,62] fp32.
//
// R5: R3 mapping (co = tid&15, 2x4 px/thread, tile 8x16, grid 512) but
// ci-OUTER over a CH=4 d-chunk so only 27 weights are register-live at a
// time (R3's wreg[81] -> VGPR 228 -> 2 waves/SIMD, VALUBusy 62%).
// Weights staged once into LDS ([16][3][28] padded, 16B-aligned, 2-way
// bank aliasing = free), reloaded per (chunk, ci) via ds_read_b128.
// Accumulator: (CH+2) output slots (slot = dd + 2 - kd, compile-time
// after unroll); slots 0..CH-1 finalize (min) each chunk, top 2 carry.
// NO launch_bounds floor (R2/R4: any cap below ~160 VGPR spills -> GBs
// of scratch traffic). Softmax via 16-lane shuffles.

#define CH 4  // d-slices per staged chunk

// taps (o,kh) for current (ci,dd,row): 3 kw x 4 p x 3 kd FMAs
// kd=0 -> slot dd+2, kd=1 -> slot dd+1, kd=2 -> slot dd
#define TAPS(o, kh)                                                        \
    _Pragma("unroll")                                                      \
    for (int kw = 0; kw < 3; ++kw) {                                       \
        const float wk0 = wreg[0  + (kh) * 3 + kw];                        \
        const float wk1 = wreg[9  + (kh) * 3 + kw];                        \
        const float wk2 = wreg[18 + (kh) * 3 + kw];                        \
        _Pragma("unroll")                                                  \
        for (int p = 0; p < 4; ++p) {                                      \
            const float xv = row[kw + p];                                  \
            ACC[dd + 2][o][p] = fmaf(xv, wk0, ACC[dd + 2][o][p]);          \
            ACC[dd + 1][o][p] = fmaf(xv, wk1, ACC[dd + 1][o][p]);          \
            ACC[dd + 0][o][p] = fmaf(xv, wk2, ACC[dd + 0][o][p]);          \
        }                                                                  \
    }

__global__ __launch_bounds__(256) void conv3d_min_softmax(
    const float* __restrict__ x,     // [16,3,64,64,64]
    const float* __restrict__ wgt,   // [16,3,3,3,3]
    const float* __restrict__ bias,  // [16]
    float* __restrict__ out)         // [16,16,62,62]
{
    const int tid = threadIdx.x;
    const int co  = tid & 15;          // output channel on lane bits 0..3
    const int s   = tid >> 4;          // 0..15 strip id
    const int hh  = (s >> 2) * 2;      // output rows hh, hh+1 (0,2,4,6)
    const int ww  = (s & 3) * 4;       // output cols ww..ww+3 (0,4,8,12)
    const int n   = blockIdx.z;
    const int h0  = blockIdx.y * 8;    // 8 h-tiles cover rows 0..63
    const int w0  = blockIdx.x * 16;   // 4 w-tiles cover cols 0..63

    // staged x: 3 ci x CH d x 10 rows x 20 cols (stride 20: f4-aligned)
    __shared__ __align__(16) float sx[3][CH][10][20];
    // weights: [co][ci][28] pad -> ci base 112 B (16B-aligned), co stride
    // 336 B; 16 co -> 2-way bank aliasing only (free per m136)
    __shared__ __align__(16) float wlds[16][3][28];

    // ---- one-time weight staging: 1296 floats ----
    for (int i = tid; i < 16 * 81; i += 256) {
        int c2 = i / 81;
        int j  = i - c2 * 81;
        int ci = j / 27;
        int t  = j - ci * 27;          // kd*9 + kh*3 + kw
        wlds[c2][ci][t] = wgt[i];
    }

    // ACC[slot][o][p]; slot = output d' - (d0 - 2), slots 0..CH+1
    float ACC[CH + 2][2][4], mv[2][4];
#pragma unroll
    for (int sl = 0; sl < CH + 2; ++sl)
#pragma unroll
        for (int o = 0; o < 2; ++o)
#pragma unroll
            for (int p = 0; p < 4; ++p) ACC[sl][o][p] = 0.f;
#pragma unroll
    for (int o = 0; o < 2; ++o)
#pragma unroll
        for (int p = 0; p < 4; ++p) mv[o][p] = 1e30f;

    const float* xn = x + (size_t)n * 3 * 64 * 64 * 64;

    for (int c = 0; c < 64 / CH; ++c) {
        const int d0 = c * CH;
        __syncthreads();   // covers weight staging before chunk 0 too
        // ---- stage 3 x CH x 10 x 18(->20): 600 float4 ----
        for (int F = tid; F < 3 * CH * 10 * 5; F += 256) {
            int rowid = F / 5;               // ci*(CH*10) + dd*10 + r
            int g     = F - rowid * 5;       // col group (4 floats)
            int ci    = rowid / (CH * 10);
            int rem   = rowid - ci * (CH * 10);
            int dd    = rem / 10;
            int r     = rem - dd * 10;
            int gh    = min(h0 + r, 63);     // clamp: edge halo, unused
            int gw    = min(w0 + g * 4, 60); // clamp: cols >=62 unused
            *(float4*)&sx[ci][dd][r][g * 4] = *(const float4*)
                &xn[(((size_t)ci * 64 + d0 + dd) * 64 + gh) * 64 + gw];
        }
        __syncthreads();

        // ---- ci-outer compute: 27 weights live at a time ----
#pragma unroll
        for (int ci = 0; ci < 3; ++ci) {
            float wreg[27];
#pragma unroll
            for (int q = 0; q < 27; ++q) wreg[q] = wlds[co][ci][q];
#pragma unroll
            for (int dd = 0; dd < CH; ++dd) {
#pragma unroll
                for (int r = 0; r < 4; ++r) {
                    const float4 a = *(const float4*)&sx[ci][dd][hh + r][ww];
                    const float2 b = *(const float2*)&sx[ci][dd][hh + r][ww + 4];
                    const float row[6] = {a.x, a.y, a.z, a.w, b.x, b.y};
                    if (r == 0) { TAPS(0, 0) }
                    if (r == 1) { TAPS(0, 1) TAPS(1, 0) }
                    if (r == 2) { TAPS(0, 2) TAPS(1, 1) }
                    if (r == 3) { TAPS(1, 2) }
                }
            }
        }

        // ---- finalize complete slots 0..CH-1 (d' = d0-2+slot), shift ----
#pragma unroll
        for (int sl = 0; sl < CH; ++sl) {
            if (d0 - 2 + sl >= 0) {          // uniform guard (chunk 0 only)
#pragma unroll
                for (int o = 0; o < 2; ++o)
#pragma unroll
                    for (int p = 0; p < 4; ++p)
                        mv[o][p] = fminf(mv[o][p], ACC[sl][o][p]);
            }
        }
#pragma unroll
        for (int o = 0; o < 2; ++o)
#pragma unroll
            for (int p = 0; p < 4; ++p) {
                ACC[0][o][p] = ACC[CH][o][p];
                ACC[1][o][p] = ACC[CH + 1][o][p];
            }
#pragma unroll
        for (int sl = 2; sl < CH + 2; ++sl)
#pragma unroll
            for (int o = 0; o < 2; ++o)
#pragma unroll
                for (int p = 0; p < 4; ++p) ACC[sl][o][p] = 0.f;
    }

    // ---- epilogue: bias, softmax over 16 channels (lanes), store ----
    const float bv = bias[co];
#pragma unroll
    for (int o = 0; o < 2; ++o) {
        const int hp = h0 + hh + o;
#pragma unroll
        for (int p = 0; p < 4; ++p) {
            float v = mv[o][p] + bv;
            float mx = v;
#pragma unroll
            for (int off = 1; off < 16; off <<= 1)
                mx = fmaxf(mx, __shfl_xor(mx, off, 64));
            float e = __expf(v - mx);
            float sum = e;
#pragma unroll
            for (int off = 1; off < 16; off <<= 1)
                sum += __shfl_xor(sum, off, 64);
            const int wp = w0 + ww + p;
            if (hp < 62 && wp < 62)
                out[(((size_t)n * 16 + co) * 62 + hp) * 62 + wp] = e / sum;
        }
    }
}

extern "C" void kernel_launch(void* const* d_in, const int* in_sizes, int n_in,
                              void* d_out, int out_size, void* d_ws, size_t ws_size,
                              hipStream_t stream) {
    const float* x    = (const float*)d_in[0];
    const float* wgt  = (const float*)d_in[1];
    const float* bias = (const float*)d_in[2];
    float* out        = (float*)d_out;
    dim3 grid(4, 8, 16);   // (w-tiles, h-tiles, n)
    dim3 block(256);
    hipLaunchKernelGGL(conv3d_min_softmax, grid, block, 0, stream,
                       x, wgt, bias, out);
}